// Round 1
// baseline (3518.102 us; speedup 1.0000x reference)
//
#include <hip/hip_runtime.h>

#define T_STEPS 128

// sigmoid(x) = 1/(1+exp(-x)) = rcp(1 + exp2(-x*log2e))
__device__ __forceinline__ float fast_sigmoid(float x) {
    float e = __builtin_amdgcn_exp2f(-1.44269504f * x);
    return __builtin_amdgcn_rcpf(1.0f + e);
}
// tanh(x) = 1 - 2/(1+exp(2x)) = 1 - 2*rcp(1 + exp2(2x*log2e))
__device__ __forceinline__ float fast_tanh(float x) {
    float e = __builtin_amdgcn_exp2f(2.88539008f * x);
    float r = __builtin_amdgcn_rcpf(1.0f + e);
    return fmaf(-2.0f, r, 1.0f);
}

// One batch element per 32-lane group; lane j owns hidden unit j.
// Per-lane W_hh rows (i,f,g,o) live in VGPRs for the whole kernel.
// h broadcast within the group via ds_swizzle (BitMode: and=0, or=K -> all
// lanes of each 32-group read lane K). Wave64 = two independent groups.
extern "C" __global__ void __launch_bounds__(256)
lstm_seqclass_kernel(const float* __restrict__ x,
                     const float* __restrict__ W_ih,
                     const float* __restrict__ W_hh,
                     const float* __restrict__ b_ih,
                     const float* __restrict__ b_hh,
                     const float* __restrict__ W_fc,
                     const float* __restrict__ b_fc,
                     float* __restrict__ out,
                     int B)
{
    int tid = blockIdx.x * 256 + threadIdx.x;
    int b   = tid >> 5;   // batch element (uniform per 32-lane group)
    int j   = tid & 31;   // hidden unit
    if (b >= B) return;

    // Per-lane weight rows: gate order i, f, g, o (PyTorch LSTMCell).
    float wi[32], wf[32], wg[32], wo[32];
    #pragma unroll
    for (int k = 0; k < 32; ++k) {
        wi[k] = W_hh[(j      ) * 32 + k];
        wf[k] = W_hh[(j + 32 ) * 32 + k];
        wg[k] = W_hh[(j + 64 ) * 32 + k];
        wo[k] = W_hh[(j + 96 ) * 32 + k];
    }
    float bi = b_ih[j     ] + b_hh[j     ];
    float bf = b_ih[j + 32] + b_hh[j + 32];
    float bg = b_ih[j + 64] + b_hh[j + 64];
    float bo = b_ih[j + 96] + b_hh[j + 96];
    float wxi = W_ih[j];
    float wxf = W_ih[j + 32];
    float wxg = W_ih[j + 64];
    float wxo = W_ih[j + 96];

    const float* xb = x + (size_t)b * T_STEPS;

    float h = 0.0f, c = 0.0f;

    for (int t = 0; t < T_STEPS; ++t) {
        float xt = xb[t];
        float gi = fmaf(xt, wxi, bi);
        float gf = fmaf(xt, wxf, bf);
        float gg = fmaf(xt, wxg, bg);
        float go = fmaf(xt, wxo, bo);

        int hbits = __float_as_int(h);
        // STEPK(K): hk = h broadcast from lane K of this 32-lane group.
        #define STEPK(K) { \
            float hk = __int_as_float(__builtin_amdgcn_ds_swizzle(hbits, ((K) << 5))); \
            gi = fmaf(wi[K], hk, gi); \
            gf = fmaf(wf[K], hk, gf); \
            gg = fmaf(wg[K], hk, gg); \
            go = fmaf(wo[K], hk, go); }
        STEPK(0)  STEPK(1)  STEPK(2)  STEPK(3)
        STEPK(4)  STEPK(5)  STEPK(6)  STEPK(7)
        STEPK(8)  STEPK(9)  STEPK(10) STEPK(11)
        STEPK(12) STEPK(13) STEPK(14) STEPK(15)
        STEPK(16) STEPK(17) STEPK(18) STEPK(19)
        STEPK(20) STEPK(21) STEPK(22) STEPK(23)
        STEPK(24) STEPK(25) STEPK(26) STEPK(27)
        STEPK(28) STEPK(29) STEPK(30) STEPK(31)
        #undef STEPK

        float si = fast_sigmoid(gi);
        float sf = fast_sigmoid(gf);
        float so = fast_sigmoid(go);
        float tg = fast_tanh(gg);
        c = fmaf(sf, c, si * tg);
        h = so * fast_tanh(c);
    }

    // FC head: out[b] = h @ W_fc.T + b_fc   (reduce over the 32-lane group)
    float o0 = h * W_fc[j];
    float o1 = h * W_fc[32 + j];
    #pragma unroll
    for (int m = 16; m >= 1; m >>= 1) {
        o0 += __shfl_xor(o0, m, 64);  // xor masks <=16 stay within 32-group
        o1 += __shfl_xor(o1, m, 64);
    }
    if (j == 0) {
        out[(size_t)b * 2 + 0] = o0 + b_fc[0];
        out[(size_t)b * 2 + 1] = o1 + b_fc[1];
    }
}

extern "C" void kernel_launch(void* const* d_in, const int* in_sizes, int n_in,
                              void* d_out, int out_size, void* d_ws, size_t ws_size,
                              hipStream_t stream) {
    const float* x    = (const float*)d_in[0];
    const float* W_ih = (const float*)d_in[1];
    const float* W_hh = (const float*)d_in[2];
    const float* b_ih = (const float*)d_in[3];
    const float* b_hh = (const float*)d_in[4];
    const float* W_fc = (const float*)d_in[5];
    const float* b_fc = (const float*)d_in[6];
    float* out = (float*)d_out;

    int B = in_sizes[0] / T_STEPS;
    int total = B * 32;
    int grid = (total + 255) / 256;
    hipLaunchKernelGGL(lstm_seqclass_kernel, dim3(grid), dim3(256), 0, stream,
                       x, W_ih, W_hh, b_ih, b_hh, W_fc, b_fc, out, B);
}

// Round 3
// 818.334 us; speedup vs baseline: 4.2991x; 4.2991x over previous
//
#include <hip/hip_runtime.h>
#include <hip/hip_bf16.h>

#define T_STEPS 128

typedef __attribute__((ext_vector_type(8))) short short8;
typedef __attribute__((ext_vector_type(4))) float f32x4;

// sigmoid(x) = rcp(1 + exp2(-x*log2e))
__device__ __forceinline__ float fast_sigmoid(float x) {
    float e = __builtin_amdgcn_exp2f(-1.44269504f * x);
    return __builtin_amdgcn_rcpf(1.0f + e);
}
// tanh(x) = 1 - 2*rcp(1 + exp2(2x*log2e))
__device__ __forceinline__ float fast_tanh(float x) {
    float e = __builtin_amdgcn_exp2f(2.88539008f * x);
    float r = __builtin_amdgcn_rcpf(1.0f + e);
    return fmaf(-2.0f, r, 1.0f);
}

// One wave = one 16-batch tile. Per step:
//   gates[16b x 128gu] = hprev[16 x 32] @ W_hh.T[32 x 128] + x_t*W_ih.T + b
// via 8 gu-blocks of mfma_f32_16x16x32_bf16 (K=32=H exactly), h split hi/lo
// (2 MFMAs/block) to kill bf16 recurrence quantization.
// Gate-block m covers gate (m>>1) in {i,f,g,o}, units j = 2*col + (m&1), so
// D-layout (col=lane&15, row=(lane>>4)*4+reg) gives each lane all 4 gates of
// its (batch,unit) pairs -> activations are lane-local.
extern "C" __global__ void __launch_bounds__(256)
lstm_mfma_kernel(const float* __restrict__ x,
                 const float* __restrict__ W_ih,
                 const float* __restrict__ W_hh,
                 const float* __restrict__ b_ih,
                 const float* __restrict__ b_hh,
                 const float* __restrict__ W_fc,
                 const float* __restrict__ b_fc,
                 float* __restrict__ out, int B)
{
    __shared__ float        xs[4][16 * 129];   // x tile, +1 pad: conflict-free t-reads
    __shared__ unsigned int hhi[4][256];       // h_hi [16 rows][16 u32] bf16x2
    __shared__ unsigned int hlo[4][256];       // h_lo

    const int widx = threadIdx.x >> 6;
    const int lane = threadIdx.x & 63;
    const int p    = lane & 15;      // tile column
    const int g4   = lane >> 4;      // quarter-wave 0..3
    const int btile = (blockIdx.x * 4 + widx) * 16;
    if (btile >= B) return;

    float*        xw = &xs[widx][0];
    unsigned int* hh = &hhi[widx][0];
    unsigned int* hl = &hlo[widx][0];

    // ---- stage x tile [16][129] f32 (coalesced global float4 reads)
    #pragma unroll
    for (int q = 0; q < 8; ++q) {
        int c   = q * 64 + lane;          // 512 chunks of 4 floats
        int row = c >> 5;
        int t0  = (c & 31) * 4;
        float4 v = *reinterpret_cast<const float4*>(x + (size_t)(btile + row) * T_STEPS + t0);
        float* dst = &xw[row * 129 + t0];
        dst[0] = v.x; dst[1] = v.y; dst[2] = v.z; dst[3] = v.w;
    }
    // zero h tiles (h0 = 0)
    #pragma unroll
    for (int q = 0; q < 4; ++q) { hh[q * 64 + lane] = 0u; hl[q * 64 + lane] = 0u; }

    // ---- per-lane constants: W_hh B-fragments (bf16 RTN), bias, W_ih
    short8 wfrag[8];
    float  biasv[8], wihv[8];
    #pragma unroll
    for (int m = 0; m < 8; ++m) {
        int gu   = (m >> 1) * 32 + 2 * p + (m & 1);
        biasv[m] = b_ih[gu] + b_hh[gu];
        wihv[m]  = W_ih[gu];
        const float* wr = W_hh + gu * 32 + g4 * 8;   // 8 consecutive k
        short8 w;
        #pragma unroll
        for (int e = 0; e < 8; ++e) {
            unsigned int bits = __float_as_uint(wr[e]);
            bits = bits + 0x7FFFu + ((bits >> 16) & 1u);   // RTN to bf16
            w[e] = (short)(bits >> 16);
        }
        wfrag[m] = w;
    }

    __builtin_amdgcn_wave_barrier();   // LDS writes above ordered before loop reads

    float cst[2][4];   // c state: [unit-half u][batch-reg r]
    float hn[2][4];
    #pragma unroll
    for (int u = 0; u < 2; ++u)
        #pragma unroll
        for (int r = 0; r < 4; ++r) cst[u][r] = 0.0f;

    for (int t = 0; t < T_STEPS; ++t) {
        // x for my 4 batch rows (broadcast reads, pad-129 -> distinct banks)
        float xt[4];
        #pragma unroll
        for (int r = 0; r < 4; ++r) xt[r] = xw[(g4 * 4 + r) * 129 + t];

        // acc init = bias + x*W_ih  (f32, exact)
        f32x4 acc[8];
        #pragma unroll
        for (int m = 0; m < 8; ++m) {
            f32x4 a;
            #pragma unroll
            for (int r = 0; r < 4; ++r) a[r] = fmaf(xt[r], wihv[m], biasv[m]);
            acc[m] = a;
        }

        // previous h as A-fragments: row=l&15 (batch), k=g4*8+e
        short8 ahi = *reinterpret_cast<short8*>(&hh[p * 16 + g4 * 4]);
        short8 alo = *reinterpret_cast<short8*>(&hl[p * 16 + g4 * 4]);

        #pragma unroll
        for (int m = 0; m < 8; ++m) {
            acc[m] = __builtin_amdgcn_mfma_f32_16x16x32_bf16(ahi, wfrag[m], acc[m], 0, 0, 0);
            acc[m] = __builtin_amdgcn_mfma_f32_16x16x32_bf16(alo, wfrag[m], acc[m], 0, 0, 0);
        }

        // activations + state update (all lane-local)
        #pragma unroll
        for (int u = 0; u < 2; ++u) {
            #pragma unroll
            for (int r = 0; r < 4; ++r) {
                float gi = acc[0 + u][r];
                float gf = acc[2 + u][r];
                float gg = acc[4 + u][r];
                float go = acc[6 + u][r];
                float cn = fmaf(fast_sigmoid(gf), cst[u][r],
                                fast_sigmoid(gi) * fast_tanh(gg));
                cst[u][r] = cn;
                hn[u][r]  = fast_sigmoid(go) * fast_tanh(cn);
            }
        }

        // pack h -> bf16 hi (truncate) + lo (residual), write to LDS
        #pragma unroll
        for (int r = 0; r < 4; ++r) {
            unsigned int x0 = __float_as_uint(hn[0][r]);
            unsigned int x1 = __float_as_uint(hn[1][r]);
            unsigned int hiw = (x0 >> 16) | (x1 & 0xFFFF0000u);
            float res0 = hn[0][r] - __uint_as_float(x0 & 0xFFFF0000u);
            float res1 = hn[1][r] - __uint_as_float(x1 & 0xFFFF0000u);
            unsigned int low = (__float_as_uint(res0) >> 16)
                             | (__float_as_uint(res1) & 0xFFFF0000u);
            int rb = g4 * 4 + r;
            hh[rb * 16 + p] = hiw;
            hl[rb * 16 + p] = low;
        }
        __builtin_amdgcn_wave_barrier();   // order writes before next iter's reads
    }

    // ---- FC head: out[b][o] = sum_j h[b][j]*W_fc[o][j] + b_fc[o]
    float wfc00 = W_fc[2 * p], wfc01 = W_fc[2 * p + 1];
    float wfc10 = W_fc[32 + 2 * p], wfc11 = W_fc[32 + 2 * p + 1];
    float bfc0 = b_fc[0], bfc1 = b_fc[1];
    #pragma unroll
    for (int r = 0; r < 4; ++r) {
        float o0 = fmaf(hn[0][r], wfc00, hn[1][r] * wfc01);
        float o1 = fmaf(hn[0][r], wfc10, hn[1][r] * wfc11);
        #pragma unroll
        for (int m = 8; m >= 1; m >>= 1) {   // reduce across p (16-lane group)
            o0 += __shfl_xor(o0, m, 64);
            o1 += __shfl_xor(o1, m, 64);
        }
        if (p == 0) {
            size_t b = (size_t)(btile + g4 * 4 + r);
            out[b * 2 + 0] = o0 + bfc0;
            out[b * 2 + 1] = o1 + bfc1;
        }
    }
}

extern "C" void kernel_launch(void* const* d_in, const int* in_sizes, int n_in,
                              void* d_out, int out_size, void* d_ws, size_t ws_size,
                              hipStream_t stream) {
    const float* x    = (const float*)d_in[0];
    const float* W_ih = (const float*)d_in[1];
    const float* W_hh = (const float*)d_in[2];
    const float* b_ih = (const float*)d_in[3];
    const float* b_hh = (const float*)d_in[4];
    const float* W_fc = (const float*)d_in[5];
    const float* b_fc = (const float*)d_in[6];
    float* out = (float*)d_out;

    int B = in_sizes[0] / T_STEPS;
    int grid = (B + 63) / 64;   // 64 batch per block (4 waves x 16)
    hipLaunchKernelGGL(lstm_mfma_kernel, dim3(grid), dim3(256), 0, stream,
                       x, W_ih, W_hh, b_ih, b_hh, W_fc, b_fc, out, B);
}